// Round 1
// baseline (3366.933 us; speedup 1.0000x reference)
//
#include <hip/hip_runtime.h>

constexpr int BATCH = 8;
constexpr int PPC   = 2048;            // points per cloud
constexpr int NPT   = BATCH * PPC;     // 16384 points
constexpr int OCH   = 64;              // out channels (= in channels)
constexpr int KNN_K = 20;
constexpr int NEDGE = NPT * KNN_K;     // 327680 edges

// ---------------------------------------------------------------- kNN ------
// One thread per point; per-thread sorted top-20 list lives in LDS columns.
// Distance formula sq_i + sq_j - 2*dot matches the reference arithmetic.
__global__ __launch_bounds__(64) void knn_kernel(const float* __restrict__ pos,
                                                 int* __restrict__ nbr) {
  __shared__ float cpx[256], cpy[256], cpz[256], csq[256];
  __shared__ float bd[KNN_K][64];
  __shared__ int   bi[KNN_K][64];
  const int t = threadIdx.x;
  const int i = blockIdx.x * 64 + t;
  const int cbase = i & ~(PPC - 1);
  const int il = i - cbase;
  const float px = pos[3 * i + 0], py = pos[3 * i + 1], pz = pos[3 * i + 2];
  const float sqi = px * px + py * py + pz * pz;
#pragma unroll
  for (int s = 0; s < KNN_K; ++s) { bd[s][t] = 1e30f; bi[s][t] = 0; }
  float worst = 1e30f;
  for (int tile = 0; tile < PPC; tile += 256) {
    __syncthreads();
    for (int u = t; u < 256; u += 64) {
      int j = cbase + tile + u;
      float ax = pos[3 * j + 0], ay = pos[3 * j + 1], az = pos[3 * j + 2];
      cpx[u] = ax; cpy[u] = ay; cpz[u] = az;
      csq[u] = ax * ax + ay * ay + az * az;
    }
    __syncthreads();
    for (int u = 0; u < 256; ++u) {
      float d2 = sqi + csq[u] - 2.0f * (px * cpx[u] + py * cpy[u] + pz * cpz[u]);
      int jl = tile + u;
      if (d2 < worst && jl != il) {
        // stable insertion: shift strictly-greater entries up; evicts the
        // largest (and latest-index among ties) -> matches top_k tie-break.
        int s = KNN_K - 2;
        while (s >= 0) {
          float v = bd[s][t];
          if (v > d2) { bd[s + 1][t] = v; bi[s + 1][t] = bi[s][t]; --s; }
          else break;
        }
        bd[s + 1][t] = d2; bi[s + 1][t] = jl;
        worst = bd[KNN_K - 1][t];
      }
    }
  }
  for (int s = 0; s < KNN_K; ++s) nbr[(size_t)i * KNN_K + s] = cbase + bi[s][t];
}

// ------------------------------------------------- node-level layer-1 GEMM -
// y[n] = x[n] @ (W1a - W1b)^T ; z[n] = x[n] @ W1b^T
// so that h1_pre(edge e=(i<-j)) = y[j] + z[i] + b1.
__global__ __launch_bounds__(256) void node_gemm(const float* __restrict__ x,
                                                 const float* __restrict__ W1,
                                                 float* __restrict__ yv,
                                                 float* __restrict__ zv) {
  __shared__ float wa[64][65];
  __shared__ float wb[64][65];
  __shared__ float xs[4][64];
  const int t = threadIdx.x;
  for (int m = t; m < 8192; m += 256) {
    int o = m >> 7, c2 = m & 127;
    float w = W1[m];
    if (c2 < 64) wa[c2][o] = w; else wb[c2 - 64][o] = w;
  }
  const int nl = t >> 6, o = t & 63;
  xs[nl][o] = x[(size_t)(blockIdx.x * 4 + nl) * 64 + o];
  __syncthreads();
  float accA = 0.f, accB = 0.f;
#pragma unroll 8
  for (int c = 0; c < 64; ++c) {
    float xv = xs[nl][c];
    accA = fmaf(xv, wa[c][o], accA);
    accB = fmaf(xv, wb[c][o], accB);
  }
  size_t n = (size_t)blockIdx.x * 4 + nl;
  yv[n * 64 + o] = accA - accB;
  zv[n * 64 + o] = accB;
}

// ------------------------------------------------------------ BN1 stats ----
__global__ __launch_bounds__(256) void bn1_stats(const int* __restrict__ nbr,
                                                 const float* __restrict__ yv,
                                                 const float* __restrict__ zv,
                                                 const float* __restrict__ b1,
                                                 float* __restrict__ stats) {
  const int t = threadIdx.x;
  const int o = t & 63, g = t >> 6;
  const float bo = b1[o];
  float s1 = 0.f, s2 = 0.f;
  for (int e = blockIdx.x * 4 + g; e < NEDGE; e += gridDim.x * 4) {
    int j  = nbr[e];
    int ic = e / KNN_K;
    float s = yv[(size_t)j * 64 + o] + zv[(size_t)ic * 64 + o] + bo;
    s1 += s; s2 += s * s;
  }
  __shared__ float red[8][64];
  red[g][o] = s1; red[g + 4][o] = s2;
  __syncthreads();
  if (g == 0) {
    float a = red[0][o] + red[1][o] + red[2][o] + red[3][o];
    float b = red[4][o] + red[5][o] + red[6][o] + red[7][o];
    atomicAdd(&stats[o], a);
    atomicAdd(&stats[64 + o], b);
  }
}

// ------------------------------------------------------- BN finalize -------
// coefout[o] = gamma*invstd ; coefout[64+o] = beta - mu*gamma*invstd
__global__ void finalize_bn(const float* __restrict__ stats,
                            const float* __restrict__ gamma,
                            const float* __restrict__ beta,
                            float invE, float* __restrict__ coefout) {
  int o = threadIdx.x;
  float mu  = stats[o] * invE;
  float var = stats[64 + o] * invE - mu * mu;
  float a   = gamma[o] * rsqrtf(var + 1e-5f);
  coefout[o]      = a;
  coefout[64 + o] = beta[o] - mu * a;
}

// --------------------------------- fused BN1-apply + GEMM2 (+stats/scatter)
// MODE 0: compute h2_pre tile, accumulate BN2 sum/sumsq, optionally store.
// MODE 1: recompute h2_pre, apply BN2+relu, atomicMax scatter by row.
template <int MODE, bool STORE>
__global__ __launch_bounds__(256) void gemm2_pass(
    const int* __restrict__ nbr, const float* __restrict__ yv,
    const float* __restrict__ zv, const float* __restrict__ b1,
    const float* __restrict__ coef1, const float* __restrict__ W2,
    const float* __restrict__ b2, float* __restrict__ h2s,
    float* __restrict__ stats2, const float* __restrict__ coef2,
    float* __restrict__ outp) {
  __shared__ float w2t[64][68];
  __shared__ float h1s[64][68];
  __shared__ float a1s[64], c1s[64], b1s[64];
  __shared__ float ss[2][64];
  const int t = threadIdx.x;
  for (int m = t; m < 4096; m += 256) {
    int o = m >> 6, c = m & 63;
    w2t[c][o] = W2[m];
  }
  if (t < 64) { a1s[t] = coef1[t]; c1s[t] = coef1[64 + t]; b1s[t] = b1[t]; }
  const int eg = t >> 4, cg = t & 15;
  const int e0l = eg * 4, o0 = cg * 4;
  float b2r[4], a2r[4], c2r[4];
#pragma unroll
  for (int q = 0; q < 4; ++q) b2r[q] = b2[o0 + q];
  if (MODE == 1) {
#pragma unroll
    for (int q = 0; q < 4; ++q) { a2r[q] = coef2[o0 + q]; c2r[q] = coef2[64 + o0 + q]; }
  }
  float s1[4] = {0, 0, 0, 0}, s2[4] = {0, 0, 0, 0};
  const int ntiles = NEDGE / 64;
  for (int tile = blockIdx.x; tile < ntiles; tile += gridDim.x) {
    __syncthreads();
    const int ebase = tile * 64;
#pragma unroll
    for (int k = 0; k < 16; ++k) {
      int m = k * 256 + t;
      int el = m >> 6, o = m & 63;
      int e = ebase + el;
      int j  = nbr[e];
      int ic = e / KNN_K;
      float s = yv[(size_t)j * 64 + o] + zv[(size_t)ic * 64 + o] + b1s[o];
      float h = fmaf(s, a1s[o], c1s[o]);
      h1s[el][o] = h > 0.f ? h : 0.f;
    }
    __syncthreads();
    float acc[4][4];
#pragma unroll
    for (int r = 0; r < 4; ++r)
#pragma unroll
      for (int q = 0; q < 4; ++q) acc[r][q] = 0.f;
#pragma unroll 8
    for (int c = 0; c < 64; ++c) {
      float a0 = h1s[e0l + 0][c], a1 = h1s[e0l + 1][c];
      float a2 = h1s[e0l + 2][c], a3 = h1s[e0l + 3][c];
      float w0 = w2t[c][o0 + 0], w1 = w2t[c][o0 + 1];
      float w2v = w2t[c][o0 + 2], w3 = w2t[c][o0 + 3];
      acc[0][0] = fmaf(a0, w0, acc[0][0]); acc[0][1] = fmaf(a0, w1, acc[0][1]);
      acc[0][2] = fmaf(a0, w2v, acc[0][2]); acc[0][3] = fmaf(a0, w3, acc[0][3]);
      acc[1][0] = fmaf(a1, w0, acc[1][0]); acc[1][1] = fmaf(a1, w1, acc[1][1]);
      acc[1][2] = fmaf(a1, w2v, acc[1][2]); acc[1][3] = fmaf(a1, w3, acc[1][3]);
      acc[2][0] = fmaf(a2, w0, acc[2][0]); acc[2][1] = fmaf(a2, w1, acc[2][1]);
      acc[2][2] = fmaf(a2, w2v, acc[2][2]); acc[2][3] = fmaf(a2, w3, acc[2][3]);
      acc[3][0] = fmaf(a3, w0, acc[3][0]); acc[3][1] = fmaf(a3, w1, acc[3][1]);
      acc[3][2] = fmaf(a3, w2v, acc[3][2]); acc[3][3] = fmaf(a3, w3, acc[3][3]);
    }
    if constexpr (MODE == 0) {
#pragma unroll
      for (int r = 0; r < 4; ++r) {
        float v0 = acc[r][0] + b2r[0];
        float v1 = acc[r][1] + b2r[1];
        float v2 = acc[r][2] + b2r[2];
        float v3 = acc[r][3] + b2r[3];
        s1[0] += v0; s1[1] += v1; s1[2] += v2; s1[3] += v3;
        s2[0] += v0 * v0; s2[1] += v1 * v1; s2[2] += v2 * v2; s2[3] += v3 * v3;
        if constexpr (STORE) {
          float4 vv = make_float4(v0, v1, v2, v3);
          *reinterpret_cast<float4*>(&h2s[(size_t)(ebase + e0l + r) * 64 + o0]) = vv;
        }
      }
    } else {
#pragma unroll
      for (int r = 0; r < 4; ++r) {
        int row = nbr[ebase + e0l + r];
        int* op = reinterpret_cast<int*>(outp) + (size_t)row * 64 + o0;
#pragma unroll
        for (int q = 0; q < 4; ++q) {
          float v = fmaf(acc[r][q] + b2r[q], a2r[q], c2r[q]);
          v = v > 0.f ? v : 0.f;
          atomicMax(op + q, __float_as_int(v));  // relu>=0 so int order == float order
        }
      }
    }
  }
  if constexpr (MODE == 0) {
    __syncthreads();
    if (t < 64) { ss[0][t] = 0.f; ss[1][t] = 0.f; }
    __syncthreads();
#pragma unroll
    for (int q = 0; q < 4; ++q) {
      s1[q] += __shfl_xor(s1[q], 16);
      s1[q] += __shfl_xor(s1[q], 32);
      s2[q] += __shfl_xor(s2[q], 16);
      s2[q] += __shfl_xor(s2[q], 32);
    }
    if ((t & 48) == 0) {
#pragma unroll
      for (int q = 0; q < 4; ++q) {
        atomicAdd(&ss[0][o0 + q], s1[q]);
        atomicAdd(&ss[1][o0 + q], s2[q]);
      }
    }
    __syncthreads();
    if (t < 64)       atomicAdd(&stats2[t], ss[0][t]);
    else if (t < 128) atomicAdd(&stats2[t - 64 + 64], ss[1][t - 64]);
  }
}

// ------------------------------------------- stored-path apply + scatter ---
__global__ __launch_bounds__(256) void apply_scatter(
    const float4* __restrict__ h2s, const float* __restrict__ coef2,
    const int* __restrict__ nbr, float* __restrict__ outp) {
  int idx = blockIdx.x * 256 + threadIdx.x;
  int e = idx >> 4;
  int o0 = (idx & 15) * 4;
  float4 v = h2s[idx];
  int row = nbr[e];
  int* op = reinterpret_cast<int*>(outp) + (size_t)row * 64 + o0;
  float r0 = fmaf(v.x, coef2[o0 + 0], coef2[64 + o0 + 0]); r0 = r0 > 0.f ? r0 : 0.f;
  float r1 = fmaf(v.y, coef2[o0 + 1], coef2[64 + o0 + 1]); r1 = r1 > 0.f ? r1 : 0.f;
  float r2 = fmaf(v.z, coef2[o0 + 2], coef2[64 + o0 + 2]); r2 = r2 > 0.f ? r2 : 0.f;
  float r3 = fmaf(v.w, coef2[o0 + 3], coef2[64 + o0 + 3]); r3 = r3 > 0.f ? r3 : 0.f;
  atomicMax(op + 0, __float_as_int(r0));
  atomicMax(op + 1, __float_as_int(r1));
  atomicMax(op + 2, __float_as_int(r2));
  atomicMax(op + 3, __float_as_int(r3));
}

// --------------------------------------------------------------- launch ----
extern "C" void kernel_launch(void* const* d_in, const int* in_sizes, int n_in,
                              void* d_out, int out_size, void* d_ws, size_t ws_size,
                              hipStream_t stream) {
  (void)in_sizes; (void)n_in;
  const float* x     = (const float*)d_in[0];
  const float* pos   = (const float*)d_in[1];
  // d_in[2] = batch (sorted equal clouds; layout hard-coded)
  const float* W1    = (const float*)d_in[3];
  const float* b1    = (const float*)d_in[4];
  const float* g1    = (const float*)d_in[5];
  const float* beta1 = (const float*)d_in[6];
  const float* W2    = (const float*)d_in[7];
  const float* b2    = (const float*)d_in[8];
  const float* g2    = (const float*)d_in[9];
  const float* beta2 = (const float*)d_in[10];
  // d_in[11] = k (device scalar) -> hard-coded KNN_K=20
  float* outp = (float*)d_out;

  char* w = (char*)d_ws;
  int*   nbr   = (int*)w;                        // 1,310,720 B
  float* yv    = (float*)(w + 1310720);          // 4,194,304 B
  float* zv    = (float*)(w + 5505024);          // 4,194,304 B
  float* stats = (float*)(w + 9699328);          // 1,024 B  ([0..127] bn1, [128..255] bn2)
  float* coef  = (float*)(w + 9700352);          // 1,024 B  ([0..127] bn1, [128..255] bn2)
  float* h2s   = (float*)(w + 9701376);          // 83,886,080 B (optional)
  const size_t NEED_BIG = 9701376ull + (size_t)NEDGE * 64 * 4;
  const bool big = ws_size >= NEED_BIG;

  hipMemsetAsync(d_out, 0, (size_t)out_size * sizeof(float), stream);
  hipMemsetAsync(stats, 0, 1024, stream);

  knn_kernel<<<NPT / 64, 64, 0, stream>>>(pos, nbr);
  node_gemm<<<NPT / 4, 256, 0, stream>>>(x, W1, yv, zv);
  bn1_stats<<<512, 256, 0, stream>>>(nbr, yv, zv, b1, stats);
  finalize_bn<<<1, 64, 0, stream>>>(stats, g1, beta1, 1.0f / NEDGE, coef);
  if (big) {
    gemm2_pass<0, true><<<1024, 256, 0, stream>>>(nbr, yv, zv, b1, coef, W2, b2,
                                                  h2s, stats + 128, nullptr, nullptr);
  } else {
    gemm2_pass<0, false><<<1024, 256, 0, stream>>>(nbr, yv, zv, b1, coef, W2, b2,
                                                   nullptr, stats + 128, nullptr, nullptr);
  }
  finalize_bn<<<1, 64, 0, stream>>>(stats + 128, g2, beta2, 1.0f / NEDGE, coef + 128);
  if (big) {
    apply_scatter<<<(NEDGE * 16) / 256, 256, 0, stream>>>(
        (const float4*)h2s, coef + 128, nbr, outp);
  } else {
    gemm2_pass<1, false><<<1024, 256, 0, stream>>>(nbr, yv, zv, b1, coef, W2, b2,
                                                   nullptr, nullptr, coef + 128, outp);
  }
}

// Round 2
// 694.028 us; speedup vs baseline: 4.8513x; 4.8513x over previous
//
#include <hip/hip_runtime.h>

constexpr int BATCH = 8;
constexpr int PPC   = 2048;            // points per cloud
constexpr int NPT   = BATCH * PPC;     // 16384 points
constexpr int OCH   = 64;              // out channels (= in channels)
constexpr int KNN_K = 20;
constexpr int NEDGE = NPT * KNN_K;     // 327680 edges

// ---------------------------------------------------------------- kNN ------
// Block = 32 points x 8 splits (256 threads). Each lane scans 256 candidates
// of its cloud keeping a register-resident sorted top-20 (predicated
// shift-insert, no LDS). The 8 lanes of a point then merge via a 20-round
// shfl_xor argmin tournament. Tie-break: smaller distance, then smaller
// split (== smaller index), matching jax top_k stability.
__global__ __launch_bounds__(256) void knn_kernel(const float* __restrict__ pos,
                                                  int* __restrict__ nbr) {
  __shared__ float4 cps[8 * 257];  // split s at s*257 (+pad) -> conflict-free
  const int t  = threadIdx.x;
  const int pl = t >> 3;                        // point-local 0..31
  const int s  = t & 7;                         // split 0..7
  const int i  = blockIdx.x * 32 + pl;          // this thread's point
  const int cbase = i & ~(PPC - 1);             // cloud base (uniform in block)

  // stage whole cloud: x,y,z,|p|^2 as float4
  for (int u = t; u < PPC; u += 256) {
    int j = cbase + u;
    float ax = pos[3 * j], ay = pos[3 * j + 1], az = pos[3 * j + 2];
    cps[(u >> 8) * 257 + (u & 255)] = make_float4(ax, ay, az, ax * ax + ay * ay + az * az);
  }
  __syncthreads();

  const float px = pos[3 * i], py = pos[3 * i + 1], pz = pos[3 * i + 2];
  const float sqi = px * px + py * py + pz * pz;
  const int il = i - cbase;

  float bd[KNN_K];
  int   bi_[KNN_K];
#pragma unroll
  for (int q = 0; q < KNN_K; ++q) { bd[q] = 1e30f; bi_[q] = 0x7fffffff; }

  const int jbase = s * 256;
  const float4* __restrict__ cp = &cps[s * 257];
  for (int u = 0; u < 256; ++u) {
    float4 c = cp[u];
    float d2 = sqi + c.w - 2.0f * (px * c.x + py * c.y + pz * c.z);
    int jl = jbase + u;
    if (d2 < bd[KNN_K - 1] && jl != il) {
      // descending predicated shift-insert; stable for ties (strict >)
#pragma unroll
      for (int q = KNN_K - 1; q > 0; --q) {
        float pv = bd[q - 1]; int pi = bi_[q - 1];
        if (pv > d2)           { bd[q] = pv; bi_[q] = pi; }
        else if (bd[q] > d2)   { bd[q] = d2; bi_[q] = jl; }
      }
      if (bd[0] > d2) { bd[0] = d2; bi_[0] = jl; }
    }
  }

  // 8-way merge by shfl tournament; winners collected in registers.
  int res[KNN_K];
#pragma unroll
  for (int r = 0; r < KNN_K; ++r) {
    float od = bd[0]; int oi = bi_[0]; int os = s;
#pragma unroll
    for (int m = 1; m < 8; m <<= 1) {
      float td = __shfl_xor(od, m, 8);
      int   ti = __shfl_xor(oi, m, 8);
      int   ts = __shfl_xor(os, m, 8);
      if (td < od || (td == od && ts < os)) { od = td; oi = ti; os = ts; }
    }
    res[r] = oi;
    if (s == os) {  // pop my head
#pragma unroll
      for (int q = 0; q < KNN_K - 1; ++q) { bd[q] = bd[q + 1]; bi_[q] = bi_[q + 1]; }
      bd[KNN_K - 1] = 1e30f;
    }
  }
  if (s == 0) {
    int4* op = reinterpret_cast<int4*>(&nbr[(size_t)i * KNN_K]);
#pragma unroll
    for (int q = 0; q < 5; ++q)
      op[q] = make_int4(cbase + res[4 * q], cbase + res[4 * q + 1],
                        cbase + res[4 * q + 2], cbase + res[4 * q + 3]);
  }
}

// ------------------------------------------------- node-level layer-1 GEMM -
// y[n] = x[n] @ (W1a - W1b)^T ; z[n] = x[n] @ W1b^T
// so that h1_pre(edge e=(i<-j)) = y[j] + z[i] + b1.
__global__ __launch_bounds__(256) void node_gemm(const float* __restrict__ x,
                                                 const float* __restrict__ W1,
                                                 float* __restrict__ yv,
                                                 float* __restrict__ zv) {
  __shared__ float wa[64][65];
  __shared__ float wb[64][65];
  __shared__ float xs[4][64];
  const int t = threadIdx.x;
  for (int m = t; m < 8192; m += 256) {
    int o = m >> 7, c2 = m & 127;
    float w = W1[m];
    if (c2 < 64) wa[c2][o] = w; else wb[c2 - 64][o] = w;
  }
  const int nl = t >> 6, o = t & 63;
  xs[nl][o] = x[(size_t)(blockIdx.x * 4 + nl) * 64 + o];
  __syncthreads();
  float accA = 0.f, accB = 0.f;
#pragma unroll 8
  for (int c = 0; c < 64; ++c) {
    float xv = xs[nl][c];
    accA = fmaf(xv, wa[c][o], accA);
    accB = fmaf(xv, wb[c][o], accB);
  }
  size_t n = (size_t)blockIdx.x * 4 + nl;
  yv[n * 64 + o] = accA - accB;
  zv[n * 64 + o] = accB;
}

// ------------------------------------------------------------ BN1 stats ----
__global__ __launch_bounds__(256) void bn1_stats(const int* __restrict__ nbr,
                                                 const float* __restrict__ yv,
                                                 const float* __restrict__ zv,
                                                 const float* __restrict__ b1,
                                                 float* __restrict__ stats) {
  const int t = threadIdx.x;
  const int o = t & 63, g = t >> 6;
  const float bo = b1[o];
  float s1 = 0.f, s2 = 0.f;
  for (int e = blockIdx.x * 4 + g; e < NEDGE; e += gridDim.x * 4) {
    int j  = nbr[e];
    int ic = e / KNN_K;
    float s = yv[(size_t)j * 64 + o] + zv[(size_t)ic * 64 + o] + bo;
    s1 += s; s2 += s * s;
  }
  __shared__ float red[8][64];
  red[g][o] = s1; red[g + 4][o] = s2;
  __syncthreads();
  if (g == 0) {
    float a = red[0][o] + red[1][o] + red[2][o] + red[3][o];
    float b = red[4][o] + red[5][o] + red[6][o] + red[7][o];
    atomicAdd(&stats[o], a);
    atomicAdd(&stats[64 + o], b);
  }
}

// ------------------------------------------------------- BN finalize -------
__global__ void finalize_bn(const float* __restrict__ stats,
                            const float* __restrict__ gamma,
                            const float* __restrict__ beta,
                            float invE, float* __restrict__ coefout) {
  int o = threadIdx.x;
  float mu  = stats[o] * invE;
  float var = stats[64 + o] * invE - mu * mu;
  float a   = gamma[o] * rsqrtf(var + 1e-5f);
  coefout[o]      = a;
  coefout[64 + o] = beta[o] - mu * a;
}

// --------------------------------- fused BN1-apply + GEMM2 (+stats/scatter)
template <int MODE, bool STORE>
__global__ __launch_bounds__(256) void gemm2_pass(
    const int* __restrict__ nbr, const float* __restrict__ yv,
    const float* __restrict__ zv, const float* __restrict__ b1,
    const float* __restrict__ coef1, const float* __restrict__ W2,
    const float* __restrict__ b2, float* __restrict__ h2s,
    float* __restrict__ stats2, const float* __restrict__ coef2,
    float* __restrict__ outp) {
  __shared__ float w2t[64][68];
  __shared__ float h1s[64][68];
  __shared__ float a1s[64], c1s[64], b1s[64];
  __shared__ float ss[2][64];
  const int t = threadIdx.x;
  for (int m = t; m < 4096; m += 256) {
    int o = m >> 6, c = m & 63;
    w2t[c][o] = W2[m];
  }
  if (t < 64) { a1s[t] = coef1[t]; c1s[t] = coef1[64 + t]; b1s[t] = b1[t]; }
  const int eg = t >> 4, cg = t & 15;
  const int e0l = eg * 4, o0 = cg * 4;
  float b2r[4], a2r[4], c2r[4];
#pragma unroll
  for (int q = 0; q < 4; ++q) b2r[q] = b2[o0 + q];
  if (MODE == 1) {
#pragma unroll
    for (int q = 0; q < 4; ++q) { a2r[q] = coef2[o0 + q]; c2r[q] = coef2[64 + o0 + q]; }
  }
  float s1[4] = {0, 0, 0, 0}, s2[4] = {0, 0, 0, 0};
  const int ntiles = NEDGE / 64;
  for (int tile = blockIdx.x; tile < ntiles; tile += gridDim.x) {
    __syncthreads();
    const int ebase = tile * 64;
#pragma unroll
    for (int k = 0; k < 16; ++k) {
      int m = k * 256 + t;
      int el = m >> 6, o = m & 63;
      int e = ebase + el;
      int j  = nbr[e];
      int ic = e / KNN_K;
      float s = yv[(size_t)j * 64 + o] + zv[(size_t)ic * 64 + o] + b1s[o];
      float h = fmaf(s, a1s[o], c1s[o]);
      h1s[el][o] = h > 0.f ? h : 0.f;
    }
    __syncthreads();
    float acc[4][4];
#pragma unroll
    for (int r = 0; r < 4; ++r)
#pragma unroll
      for (int q = 0; q < 4; ++q) acc[r][q] = 0.f;
#pragma unroll 8
    for (int c = 0; c < 64; ++c) {
      float a0 = h1s[e0l + 0][c], a1 = h1s[e0l + 1][c];
      float a2 = h1s[e0l + 2][c], a3 = h1s[e0l + 3][c];
      float w0 = w2t[c][o0 + 0], w1 = w2t[c][o0 + 1];
      float w2v = w2t[c][o0 + 2], w3 = w2t[c][o0 + 3];
      acc[0][0] = fmaf(a0, w0, acc[0][0]); acc[0][1] = fmaf(a0, w1, acc[0][1]);
      acc[0][2] = fmaf(a0, w2v, acc[0][2]); acc[0][3] = fmaf(a0, w3, acc[0][3]);
      acc[1][0] = fmaf(a1, w0, acc[1][0]); acc[1][1] = fmaf(a1, w1, acc[1][1]);
      acc[1][2] = fmaf(a1, w2v, acc[1][2]); acc[1][3] = fmaf(a1, w3, acc[1][3]);
      acc[2][0] = fmaf(a2, w0, acc[2][0]); acc[2][1] = fmaf(a2, w1, acc[2][1]);
      acc[2][2] = fmaf(a2, w2v, acc[2][2]); acc[2][3] = fmaf(a2, w3, acc[2][3]);
      acc[3][0] = fmaf(a3, w0, acc[3][0]); acc[3][1] = fmaf(a3, w1, acc[3][1]);
      acc[3][2] = fmaf(a3, w2v, acc[3][2]); acc[3][3] = fmaf(a3, w3, acc[3][3]);
    }
    if constexpr (MODE == 0) {
#pragma unroll
      for (int r = 0; r < 4; ++r) {
        float v0 = acc[r][0] + b2r[0];
        float v1 = acc[r][1] + b2r[1];
        float v2 = acc[r][2] + b2r[2];
        float v3 = acc[r][3] + b2r[3];
        s1[0] += v0; s1[1] += v1; s1[2] += v2; s1[3] += v3;
        s2[0] += v0 * v0; s2[1] += v1 * v1; s2[2] += v2 * v2; s2[3] += v3 * v3;
        if constexpr (STORE) {
          float4 vv = make_float4(v0, v1, v2, v3);
          *reinterpret_cast<float4*>(&h2s[(size_t)(ebase + e0l + r) * 64 + o0]) = vv;
        }
      }
    } else {
#pragma unroll
      for (int r = 0; r < 4; ++r) {
        int row = nbr[ebase + e0l + r];
        int* op = reinterpret_cast<int*>(outp) + (size_t)row * 64 + o0;
#pragma unroll
        for (int q = 0; q < 4; ++q) {
          float v = fmaf(acc[r][q] + b2r[q], a2r[q], c2r[q]);
          v = v > 0.f ? v : 0.f;
          atomicMax(op + q, __float_as_int(v));
        }
      }
    }
  }
  if constexpr (MODE == 0) {
    __syncthreads();
    if (t < 64) { ss[0][t] = 0.f; ss[1][t] = 0.f; }
    __syncthreads();
#pragma unroll
    for (int q = 0; q < 4; ++q) {
      s1[q] += __shfl_xor(s1[q], 16);
      s1[q] += __shfl_xor(s1[q], 32);
      s2[q] += __shfl_xor(s2[q], 16);
      s2[q] += __shfl_xor(s2[q], 32);
    }
    if ((t & 48) == 0) {
#pragma unroll
      for (int q = 0; q < 4; ++q) {
        atomicAdd(&ss[0][o0 + q], s1[q]);
        atomicAdd(&ss[1][o0 + q], s2[q]);
      }
    }
    __syncthreads();
    if (t < 64)       atomicAdd(&stats2[t], ss[0][t]);
    else if (t < 128) atomicAdd(&stats2[t - 64 + 64], ss[1][t - 64]);
  }
}

// ------------------------------------------- stored-path apply + scatter ---
__global__ __launch_bounds__(256) void apply_scatter(
    const float4* __restrict__ h2s, const float* __restrict__ coef2,
    const int* __restrict__ nbr, float* __restrict__ outp) {
  int idx = blockIdx.x * 256 + threadIdx.x;
  int e = idx >> 4;
  int o0 = (idx & 15) * 4;
  float4 v = h2s[idx];
  int row = nbr[e];
  int* op = reinterpret_cast<int*>(outp) + (size_t)row * 64 + o0;
  float r0 = fmaf(v.x, coef2[o0 + 0], coef2[64 + o0 + 0]); r0 = r0 > 0.f ? r0 : 0.f;
  float r1 = fmaf(v.y, coef2[o0 + 1], coef2[64 + o0 + 1]); r1 = r1 > 0.f ? r1 : 0.f;
  float r2 = fmaf(v.z, coef2[o0 + 2], coef2[64 + o0 + 2]); r2 = r2 > 0.f ? r2 : 0.f;
  float r3 = fmaf(v.w, coef2[o0 + 3], coef2[64 + o0 + 3]); r3 = r3 > 0.f ? r3 : 0.f;
  atomicMax(op + 0, __float_as_int(r0));
  atomicMax(op + 1, __float_as_int(r1));
  atomicMax(op + 2, __float_as_int(r2));
  atomicMax(op + 3, __float_as_int(r3));
}

// --------------------------------------------------------------- launch ----
extern "C" void kernel_launch(void* const* d_in, const int* in_sizes, int n_in,
                              void* d_out, int out_size, void* d_ws, size_t ws_size,
                              hipStream_t stream) {
  (void)in_sizes; (void)n_in;
  const float* x     = (const float*)d_in[0];
  const float* pos   = (const float*)d_in[1];
  const float* W1    = (const float*)d_in[3];
  const float* b1    = (const float*)d_in[4];
  const float* g1    = (const float*)d_in[5];
  const float* beta1 = (const float*)d_in[6];
  const float* W2    = (const float*)d_in[7];
  const float* b2    = (const float*)d_in[8];
  const float* g2    = (const float*)d_in[9];
  const float* beta2 = (const float*)d_in[10];
  float* outp = (float*)d_out;

  char* w = (char*)d_ws;
  int*   nbr   = (int*)w;                        // 1,310,720 B
  float* yv    = (float*)(w + 1310720);          // 4,194,304 B
  float* zv    = (float*)(w + 5505024);          // 4,194,304 B
  float* stats = (float*)(w + 9699328);          // 1,024 B
  float* coef  = (float*)(w + 9700352);          // 1,024 B
  float* h2s   = (float*)(w + 9701376);          // 83,886,080 B (optional)
  const size_t NEED_BIG = 9701376ull + (size_t)NEDGE * 64 * 4;
  const bool big = ws_size >= NEED_BIG;

  hipMemsetAsync(d_out, 0, (size_t)out_size * sizeof(float), stream);
  hipMemsetAsync(stats, 0, 1024, stream);

  knn_kernel<<<NPT / 32, 256, 0, stream>>>(pos, nbr);
  node_gemm<<<NPT / 4, 256, 0, stream>>>(x, W1, yv, zv);
  bn1_stats<<<512, 256, 0, stream>>>(nbr, yv, zv, b1, stats);
  finalize_bn<<<1, 64, 0, stream>>>(stats, g1, beta1, 1.0f / NEDGE, coef);
  if (big) {
    gemm2_pass<0, true><<<1024, 256, 0, stream>>>(nbr, yv, zv, b1, coef, W2, b2,
                                                  h2s, stats + 128, nullptr, nullptr);
  } else {
    gemm2_pass<0, false><<<1024, 256, 0, stream>>>(nbr, yv, zv, b1, coef, W2, b2,
                                                   nullptr, stats + 128, nullptr, nullptr);
  }
  finalize_bn<<<1, 64, 0, stream>>>(stats + 128, g2, beta2, 1.0f / NEDGE, coef + 128);
  if (big) {
    apply_scatter<<<(NEDGE * 16) / 256, 256, 0, stream>>>(
        (const float4*)h2s, coef + 128, nbr, outp);
  } else {
    gemm2_pass<1, false><<<1024, 256, 0, stream>>>(nbr, yv, zv, b1, coef, W2, b2,
                                                   nullptr, nullptr, coef + 128, outp);
  }
}

// Round 3
// 500.485 us; speedup vs baseline: 6.7273x; 1.3867x over previous
//
#include <hip/hip_runtime.h>

constexpr int BATCH = 8;
constexpr int PPC   = 2048;            // points per cloud
constexpr int NPT   = BATCH * PPC;     // 16384 points
constexpr int OCH   = 64;              // out channels (= in channels)
constexpr int KNN_K = 20;
constexpr int NEDGE = NPT * KNN_K;     // 327680 edges
constexpr int REVCAP = 128;            // per-row reverse-adjacency capacity
constexpr int OVCAP  = 8192;           // overflow list capacity

// ---------------------------------------------------------------- kNN ------
// Block = 32 points x 8 splits (256 threads). Each lane scans 256 candidates
// keeping a register-resident sorted top-20 of packed u64 keys
// (d2_bits<<32 | index) -- branch-free cndmask insert, no divergence.
// Key ordering == (d2, index) ascending == jax top_k tie-break exactly.
__global__ __launch_bounds__(256) void knn_kernel(const float* __restrict__ pos,
                                                  int* __restrict__ nbr) {
  __shared__ float4 cps[8 * 257];  // split s at s*257 (+pad) -> conflict-free
  const int t  = threadIdx.x;
  const int pl = t >> 3;                        // point-local 0..31
  const int s  = t & 7;                         // split 0..7
  const int i  = blockIdx.x * 32 + pl;          // this thread's point
  const int cbase = i & ~(PPC - 1);             // cloud base (uniform in block)

  for (int u = t; u < PPC; u += 256) {
    int j = cbase + u;
    float ax = pos[3 * j], ay = pos[3 * j + 1], az = pos[3 * j + 2];
    cps[(u >> 8) * 257 + (u & 255)] = make_float4(ax, ay, az, ax * ax + ay * ay + az * az);
  }
  __syncthreads();

  const int il = i - cbase;
  const float4 me = cps[(il >> 8) * 257 + (il & 255)];
  const float px = me.x, py = me.y, pz = me.z, sqi = me.w;

  unsigned long long kd[KNN_K];
#pragma unroll
  for (int q = 0; q < KNN_K; ++q) kd[q] = ~0ull;

  const int jbase = s * 256;
  const float4* __restrict__ cp = &cps[s * 257];
  for (int u = 0; u < 256; ++u) {
    float4 c = cp[u];
    float d2 = sqi + c.w - 2.0f * (px * c.x + py * c.y + pz * c.z);
    d2 = d2 > 0.f ? d2 : 0.f;
    int jl = jbase + u;
    unsigned long long ck =
        ((unsigned long long)__float_as_uint(d2) << 32) | (unsigned)jl;
    ck = (jl == il) ? ~0ull : ck;
    // branch-free sorted insert (ascending): exactly one slot takes ck.
#pragma unroll
    for (int q = KNN_K - 1; q > 0; --q) {
      unsigned long long lo = kd[q] < ck ? kd[q] : ck;
      kd[q] = (ck < kd[q - 1]) ? kd[q - 1] : lo;
    }
    kd[0] = kd[0] < ck ? kd[0] : ck;
  }

  // 8-way merge: 20 rounds of width-8 min-tournament on the list heads.
  int res[KNN_K];
#pragma unroll
  for (int r = 0; r < KNN_K; ++r) {
    unsigned long long w = kd[0];
#pragma unroll
    for (int m = 1; m < 8; m <<= 1) {
      unsigned int lo_ = (unsigned)__shfl_xor((int)(unsigned)w, m, 8);
      unsigned int hi_ = (unsigned)__shfl_xor((int)(unsigned)(w >> 32), m, 8);
      unsigned long long o = ((unsigned long long)hi_ << 32) | lo_;
      w = o < w ? o : w;
    }
    res[r] = (int)(unsigned)w;             // low 32 bits = local index
    bool mine = (kd[0] == w);              // keys unique -> exactly one lane
#pragma unroll
    for (int q = 0; q < KNN_K - 1; ++q) kd[q] = mine ? kd[q + 1] : kd[q];
    kd[KNN_K - 1] = mine ? ~0ull : kd[KNN_K - 1];
  }
  if (s == 0) {
    int4* op = reinterpret_cast<int4*>(&nbr[(size_t)i * KNN_K]);
#pragma unroll
    for (int q = 0; q < 5; ++q)
      op[q] = make_int4(cbase + res[4 * q], cbase + res[4 * q + 1],
                        cbase + res[4 * q + 2], cbase + res[4 * q + 3]);
  }
}

// ------------------------------------------------- node-level layer-1 GEMM -
__global__ __launch_bounds__(256) void node_gemm(const float* __restrict__ x,
                                                 const float* __restrict__ W1,
                                                 float* __restrict__ yv,
                                                 float* __restrict__ zv) {
  __shared__ float wa[64][65];
  __shared__ float wb[64][65];
  __shared__ float xs[4][64];
  const int t = threadIdx.x;
  for (int m = t; m < 8192; m += 256) {
    int o = m >> 7, c2 = m & 127;
    float w = W1[m];
    if (c2 < 64) wa[c2][o] = w; else wb[c2 - 64][o] = w;
  }
  const int nl = t >> 6, o = t & 63;
  xs[nl][o] = x[(size_t)(blockIdx.x * 4 + nl) * 64 + o];
  __syncthreads();
  float accA = 0.f, accB = 0.f;
#pragma unroll 8
  for (int c = 0; c < 64; ++c) {
    float xv = xs[nl][c];
    accA = fmaf(xv, wa[c][o], accA);
    accB = fmaf(xv, wb[c][o], accB);
  }
  size_t n = (size_t)blockIdx.x * 4 + nl;
  yv[n * 64 + o] = accA - accB;
  zv[n * 64 + o] = accB;
}

// ------------------------------------- BN1 stats + reverse-adjacency fill --
__global__ __launch_bounds__(256) void bn1_stats(const int* __restrict__ nbr,
                                                 const float* __restrict__ yv,
                                                 const float* __restrict__ zv,
                                                 const float* __restrict__ b1,
                                                 float* __restrict__ stats,
                                                 int* __restrict__ cnt,
                                                 int* __restrict__ ovf_cnt,
                                                 int* __restrict__ ovf,
                                                 int* __restrict__ rev) {
  const int t = threadIdx.x;
  const int o = t & 63, g = t >> 6;
  const float bo = b1[o];
  float s1 = 0.f, s2 = 0.f;
  for (int e = blockIdx.x * 4 + g; e < NEDGE; e += gridDim.x * 4) {
    int j  = nbr[e];
    int ic = e / KNN_K;
    if (o == 0) {  // reverse-CSR fill: one lane per edge
      int slot = atomicAdd(&cnt[j], 1);
      if (slot < REVCAP) rev[j * REVCAP + slot] = e;
      else { int ov = atomicAdd(ovf_cnt, 1); if (ov < OVCAP) ovf[ov] = e; }
    }
    float s = yv[(size_t)j * 64 + o] + zv[(size_t)ic * 64 + o] + bo;
    s1 += s; s2 += s * s;
  }
  __shared__ float red[8][64];
  red[g][o] = s1; red[g + 4][o] = s2;
  __syncthreads();
  if (g == 0) {
    float a = red[0][o] + red[1][o] + red[2][o] + red[3][o];
    float b = red[4][o] + red[5][o] + red[6][o] + red[7][o];
    atomicAdd(&stats[o], a);
    atomicAdd(&stats[64 + o], b);
  }
}

// --------------------------------- fused BN1-apply + GEMM2 (+stats/scatter)
// MODE 0: compute h2_pre tile, accumulate BN2 sum/sumsq, optionally store.
// MODE 1 (fallback, no h2s): recompute, apply BN2+relu, atomicMax scatter.
// coef1 computed per-block from raw stats (finalize kernel folded in).
template <int MODE, bool STORE>
__global__ __launch_bounds__(256) void gemm2_pass(
    const int* __restrict__ nbr, const float* __restrict__ yv,
    const float* __restrict__ zv, const float* __restrict__ b1,
    const float* __restrict__ stats1, const float* __restrict__ g1,
    const float* __restrict__ beta1, const float* __restrict__ W2,
    const float* __restrict__ b2, float* __restrict__ h2s,
    float* __restrict__ stats2, const float* __restrict__ g2,
    const float* __restrict__ beta2, float* __restrict__ outp) {
  __shared__ float w2t[64][68];
  __shared__ float h1s[64][68];
  __shared__ float a1s[64], c1s[64], b1s[64];
  __shared__ float ss[2][64];
  const int t = threadIdx.x;
  constexpr float invE = 1.0f / NEDGE;
  for (int m = t; m < 4096; m += 256) {
    int o = m >> 6, c = m & 63;
    w2t[c][o] = W2[m];
  }
  if (t < 64) {
    float mu  = stats1[t] * invE;
    float var = stats1[64 + t] * invE - mu * mu;
    float a   = g1[t] * rsqrtf(var + 1e-5f);
    a1s[t] = a; c1s[t] = beta1[t] - mu * a; b1s[t] = b1[t];
  }
  const int eg = t >> 4, cg = t & 15;
  const int e0l = eg * 4, o0 = cg * 4;
  float b2r[4], a2r[4], c2r[4];
#pragma unroll
  for (int q = 0; q < 4; ++q) b2r[q] = b2[o0 + q];
  if (MODE == 1) {
#pragma unroll
    for (int q = 0; q < 4; ++q) {
      float mu  = stats2[o0 + q] * invE;
      float var = stats2[64 + o0 + q] * invE - mu * mu;
      float a   = g2[o0 + q] * rsqrtf(var + 1e-5f);
      a2r[q] = a; c2r[q] = beta2[o0 + q] - mu * a;
    }
  }
  float s1[4] = {0, 0, 0, 0}, s2[4] = {0, 0, 0, 0};
  const int ntiles = NEDGE / 64;
  for (int tile = blockIdx.x; tile < ntiles; tile += gridDim.x) {
    __syncthreads();
    const int ebase = tile * 64;
#pragma unroll
    for (int k = 0; k < 16; ++k) {
      int m = k * 256 + t;
      int el = m >> 6, o = m & 63;
      int e = ebase + el;
      int j  = nbr[e];
      int ic = e / KNN_K;
      float s = yv[(size_t)j * 64 + o] + zv[(size_t)ic * 64 + o] + b1s[o];
      float h = fmaf(s, a1s[o], c1s[o]);
      h1s[el][o] = h > 0.f ? h : 0.f;
    }
    __syncthreads();
    float acc[4][4];
#pragma unroll
    for (int r = 0; r < 4; ++r)
#pragma unroll
      for (int q = 0; q < 4; ++q) acc[r][q] = 0.f;
#pragma unroll 8
    for (int c = 0; c < 64; ++c) {
      float a0 = h1s[e0l + 0][c], a1 = h1s[e0l + 1][c];
      float a2 = h1s[e0l + 2][c], a3 = h1s[e0l + 3][c];
      float w0 = w2t[c][o0 + 0], w1 = w2t[c][o0 + 1];
      float w2v = w2t[c][o0 + 2], w3 = w2t[c][o0 + 3];
      acc[0][0] = fmaf(a0, w0, acc[0][0]); acc[0][1] = fmaf(a0, w1, acc[0][1]);
      acc[0][2] = fmaf(a0, w2v, acc[0][2]); acc[0][3] = fmaf(a0, w3, acc[0][3]);
      acc[1][0] = fmaf(a1, w0, acc[1][0]); acc[1][1] = fmaf(a1, w1, acc[1][1]);
      acc[1][2] = fmaf(a1, w2v, acc[1][2]); acc[1][3] = fmaf(a1, w3, acc[1][3]);
      acc[2][0] = fmaf(a2, w0, acc[2][0]); acc[2][1] = fmaf(a2, w1, acc[2][1]);
      acc[2][2] = fmaf(a2, w2v, acc[2][2]); acc[2][3] = fmaf(a2, w3, acc[2][3]);
      acc[3][0] = fmaf(a3, w0, acc[3][0]); acc[3][1] = fmaf(a3, w1, acc[3][1]);
      acc[3][2] = fmaf(a3, w2v, acc[3][2]); acc[3][3] = fmaf(a3, w3, acc[3][3]);
    }
    if constexpr (MODE == 0) {
#pragma unroll
      for (int r = 0; r < 4; ++r) {
        float v0 = acc[r][0] + b2r[0];
        float v1 = acc[r][1] + b2r[1];
        float v2 = acc[r][2] + b2r[2];
        float v3 = acc[r][3] + b2r[3];
        s1[0] += v0; s1[1] += v1; s1[2] += v2; s1[3] += v3;
        s2[0] += v0 * v0; s2[1] += v1 * v1; s2[2] += v2 * v2; s2[3] += v3 * v3;
        if constexpr (STORE) {
          float4 vv = make_float4(v0, v1, v2, v3);
          *reinterpret_cast<float4*>(&h2s[(size_t)(ebase + e0l + r) * 64 + o0]) = vv;
        }
      }
    } else {
#pragma unroll
      for (int r = 0; r < 4; ++r) {
        int row = nbr[ebase + e0l + r];
        int* op = reinterpret_cast<int*>(outp) + (size_t)row * 64 + o0;
#pragma unroll
        for (int q = 0; q < 4; ++q) {
          float v = fmaf(acc[r][q] + b2r[q], a2r[q], c2r[q]);
          v = v > 0.f ? v : 0.f;
          atomicMax(op + q, __float_as_int(v));
        }
      }
    }
  }
  if constexpr (MODE == 0) {
    __syncthreads();
    if (t < 64) { ss[0][t] = 0.f; ss[1][t] = 0.f; }
    __syncthreads();
#pragma unroll
    for (int q = 0; q < 4; ++q) {
      s1[q] += __shfl_xor(s1[q], 16);
      s1[q] += __shfl_xor(s1[q], 32);
      s2[q] += __shfl_xor(s2[q], 16);
      s2[q] += __shfl_xor(s2[q], 32);
    }
    if ((t & 48) == 0) {
#pragma unroll
      for (int q = 0; q < 4; ++q) {
        atomicAdd(&ss[0][o0 + q], s1[q]);
        atomicAdd(&ss[1][o0 + q], s2[q]);
      }
    }
    __syncthreads();
    if (t < 64)       atomicAdd(&stats2[t], ss[0][t]);
    else if (t < 128) atomicAdd(&stats2[t - 64 + 64], ss[1][t - 64]);
  }
}

// ---------------------------- per-row gather: BN2 apply + relu + max + store
// One wave per output row (lane = channel). No output atomics.
__global__ __launch_bounds__(256) void gather_out(
    const float* __restrict__ h2s, const float* __restrict__ stats2,
    const float* __restrict__ g2, const float* __restrict__ beta2,
    const int* __restrict__ cnt, const int* __restrict__ rev,
    const int* __restrict__ ovf_cnt, const int* __restrict__ ovf,
    const int* __restrict__ nbr, float* __restrict__ outp) {
  const int lane = threadIdx.x & 63;
  const int row  = blockIdx.x * 4 + (threadIdx.x >> 6);
  constexpr float invE = 1.0f / NEDGE;
  float mu  = stats2[lane] * invE;
  float var = stats2[64 + lane] * invE - mu * mu;
  float a2  = g2[lane] * rsqrtf(var + 1e-5f);
  float c2  = beta2[lane] - mu * a2;
  float m = 0.f;  // relu floor doubles as empty-segment value
  int n = cnt[row]; n = n > REVCAP ? REVCAP : n;
  const int* rv = &rev[(size_t)row * REVCAP];
  for (int u = 0; u < n; ++u) {
    int e = rv[u];
    float v = h2s[(size_t)e * 64 + lane];
    float r = fmaf(v, a2, c2);
    m = r > m ? r : m;
  }
  int ov = ovf_cnt[0]; ov = ov > OVCAP ? OVCAP : ov;
  for (int u = 0; u < ov; ++u) {
    int e = ovf[u];
    if (nbr[e] == row) {
      float v = h2s[(size_t)e * 64 + lane];
      float r = fmaf(v, a2, c2);
      m = r > m ? r : m;
    }
  }
  outp[(size_t)row * 64 + lane] = m;
}

// --------------------------------------------------------------- launch ----
extern "C" void kernel_launch(void* const* d_in, const int* in_sizes, int n_in,
                              void* d_out, int out_size, void* d_ws, size_t ws_size,
                              hipStream_t stream) {
  (void)in_sizes; (void)n_in;
  const float* x     = (const float*)d_in[0];
  const float* pos   = (const float*)d_in[1];
  const float* W1    = (const float*)d_in[3];
  const float* b1    = (const float*)d_in[4];
  const float* g1    = (const float*)d_in[5];
  const float* beta1 = (const float*)d_in[6];
  const float* W2    = (const float*)d_in[7];
  const float* b2    = (const float*)d_in[8];
  const float* g2    = (const float*)d_in[9];
  const float* beta2 = (const float*)d_in[10];
  float* outp = (float*)d_out;

  char* w = (char*)d_ws;
  int*   nbr     = (int*)w;                            // 1,310,720 B
  float* yv      = (float*)(w + 1310720);              // 4,194,304 B
  float* zv      = (float*)(w + 5505024);              // 4,194,304 B
  float* stats   = (float*)(w + 9699328);              // 1,024 B ([0..127] bn1, [128..255] bn2)
  int*   cnt     = (int*)(w + 9700352);                // 65,536 B
  int*   ovf_cnt = (int*)(w + 9765888);                // 64 B
  int*   ovf     = (int*)(w + 9765952);                // 32,768 B
  int*   rev     = (int*)(w + 9798720);                // 8,388,608 B
  float* h2s     = (float*)(w + 18187328);             // 83,886,080 B (optional)
  const size_t NEED_BIG = 18187328ull + (size_t)NEDGE * 64 * 4;
  const bool big = ws_size >= NEED_BIG;

  hipMemsetAsync(stats, 0, 1024, stream);
  hipMemsetAsync(cnt, 0, 65536 + 64, stream);

  knn_kernel<<<NPT / 32, 256, 0, stream>>>(pos, nbr);
  node_gemm<<<NPT / 4, 256, 0, stream>>>(x, W1, yv, zv);
  bn1_stats<<<512, 256, 0, stream>>>(nbr, yv, zv, b1, stats, cnt, ovf_cnt, ovf, rev);
  if (big) {
    gemm2_pass<0, true><<<1024, 256, 0, stream>>>(
        nbr, yv, zv, b1, stats, g1, beta1, W2, b2, h2s, stats + 128, g2, beta2, nullptr);
    gather_out<<<NPT / 4, 256, 0, stream>>>(
        h2s, stats + 128, g2, beta2, cnt, rev, ovf_cnt, ovf, nbr, outp);
  } else {
    hipMemsetAsync(d_out, 0, (size_t)out_size * sizeof(float), stream);
    gemm2_pass<0, false><<<1024, 256, 0, stream>>>(
        nbr, yv, zv, b1, stats, g1, beta1, W2, b2, nullptr, stats + 128, g2, beta2, nullptr);
    gemm2_pass<1, false><<<1024, 256, 0, stream>>>(
        nbr, yv, zv, b1, stats, g1, beta1, W2, b2, nullptr, stats + 128, g2, beta2, outp);
  }
}

// Round 4
// 376.046 us; speedup vs baseline: 8.9535x; 1.3309x over previous
//
#include <hip/hip_runtime.h>

constexpr int BATCH = 8;
constexpr int PPC   = 2048;            // points per cloud
constexpr int NPT   = BATCH * PPC;     // 16384 points
constexpr int OCH   = 64;              // out channels (= in channels)
constexpr int KNN_K = 20;
constexpr int NEDGE = NPT * KNN_K;     // 327680 edges
constexpr int REVCAP = 128;            // per-row reverse-adjacency capacity
constexpr int OVCAP  = 8192;           // overflow list capacity

// ---------------------------------------------------------------- kNN ------
// Block = 32 points x 8 splits (256 threads). Register-resident sorted top-20
// of packed u64 keys (d2_bits<<32 | index), branch-free cndmask insert.
// Also fills the reverse adjacency (cnt/rev) from registers at the end.
__global__ __launch_bounds__(256) void knn_kernel(const float* __restrict__ pos,
                                                  int* __restrict__ nbr,
                                                  int* __restrict__ cnt,
                                                  int* __restrict__ ovf_cnt,
                                                  int* __restrict__ ovf,
                                                  int* __restrict__ rev) {
  __shared__ float4 cps[8 * 257];  // split s at s*257 (+pad) -> conflict-free
  const int t  = threadIdx.x;
  const int pl = t >> 3;                        // point-local 0..31
  const int s  = t & 7;                         // split 0..7
  const int i  = blockIdx.x * 32 + pl;          // this thread's point
  const int cbase = i & ~(PPC - 1);             // cloud base (uniform in block)

  for (int u = t; u < PPC; u += 256) {
    int j = cbase + u;
    float ax = pos[3 * j], ay = pos[3 * j + 1], az = pos[3 * j + 2];
    cps[(u >> 8) * 257 + (u & 255)] = make_float4(ax, ay, az, ax * ax + ay * ay + az * az);
  }
  __syncthreads();

  const int il = i - cbase;
  const float4 me = cps[(il >> 8) * 257 + (il & 255)];
  const float px = me.x, py = me.y, pz = me.z, sqi = me.w;

  unsigned long long kd[KNN_K];
#pragma unroll
  for (int q = 0; q < KNN_K; ++q) kd[q] = ~0ull;

  const int jbase = s * 256;
  const float4* __restrict__ cp = &cps[s * 257];
  for (int u = 0; u < 256; ++u) {
    float4 c = cp[u];
    float d2 = sqi + c.w - 2.0f * (px * c.x + py * c.y + pz * c.z);
    d2 = d2 > 0.f ? d2 : 0.f;
    int jl = jbase + u;
    unsigned long long ck =
        ((unsigned long long)__float_as_uint(d2) << 32) | (unsigned)jl;
    ck = (jl == il) ? ~0ull : ck;
#pragma unroll
    for (int q = KNN_K - 1; q > 0; --q) {
      unsigned long long lo = kd[q] < ck ? kd[q] : ck;
      kd[q] = (ck < kd[q - 1]) ? kd[q - 1] : lo;
    }
    kd[0] = kd[0] < ck ? kd[0] : ck;
  }

  // 8-way merge: 20 rounds of width-8 min-tournament on the list heads.
  int res[KNN_K];
#pragma unroll
  for (int r = 0; r < KNN_K; ++r) {
    unsigned long long w = kd[0];
#pragma unroll
    for (int m = 1; m < 8; m <<= 1) {
      unsigned int lo_ = (unsigned)__shfl_xor((int)(unsigned)w, m, 8);
      unsigned int hi_ = (unsigned)__shfl_xor((int)(unsigned)(w >> 32), m, 8);
      unsigned long long o = ((unsigned long long)hi_ << 32) | lo_;
      w = o < w ? o : w;
    }
    res[r] = (int)(unsigned)w;             // low 32 bits = local index
    bool mine = (kd[0] == w);              // keys unique -> exactly one lane
#pragma unroll
    for (int q = 0; q < KNN_K - 1; ++q) kd[q] = mine ? kd[q + 1] : kd[q];
    kd[KNN_K - 1] = mine ? ~0ull : kd[KNN_K - 1];
  }
  if (s == 0) {
    int4* op = reinterpret_cast<int4*>(&nbr[(size_t)i * KNN_K]);
#pragma unroll
    for (int q = 0; q < 5; ++q)
      op[q] = make_int4(cbase + res[4 * q], cbase + res[4 * q + 1],
                        cbase + res[4 * q + 2], cbase + res[4 * q + 3]);
  }
  // reverse-CSR fill from registers: lane s handles q = s, s+8, s+16
#pragma unroll
  for (int q0 = 0; q0 < 3; ++q0) {
    int q = s + q0 * 8;
    if (q < KNN_K) {
      int j = cbase + res[q];
      int e = i * KNN_K + q;
      int slot = atomicAdd(&cnt[j], 1);
      if (slot < REVCAP) rev[j * REVCAP + slot] = e;
      else { int ov = atomicAdd(ovf_cnt, 1); if (ov < OVCAP) ovf[ov] = e; }
    }
  }
}

// ------------------------------------------------- node-level layer-1 GEMM -
__global__ __launch_bounds__(256) void node_gemm(const float* __restrict__ x,
                                                 const float* __restrict__ W1,
                                                 float* __restrict__ yv,
                                                 float* __restrict__ zv) {
  __shared__ float wa[64][65];
  __shared__ float wb[64][65];
  __shared__ float xs[4][64];
  const int t = threadIdx.x;
  for (int m = t; m < 8192; m += 256) {
    int o = m >> 7, c2 = m & 127;
    float w = W1[m];
    if (c2 < 64) wa[c2][o] = w; else wb[c2 - 64][o] = w;
  }
  const int nl = t >> 6, o = t & 63;
  xs[nl][o] = x[(size_t)(blockIdx.x * 4 + nl) * 64 + o];
  __syncthreads();
  float accA = 0.f, accB = 0.f;
#pragma unroll 8
  for (int c = 0; c < 64; ++c) {
    float xv = xs[nl][c];
    accA = fmaf(xv, wa[c][o], accA);
    accB = fmaf(xv, wb[c][o], accB);
  }
  size_t n = (size_t)blockIdx.x * 4 + nl;
  yv[n * 64 + o] = accA - accB;
  zv[n * 64 + o] = accB;
}

// ------------------------------------------------------------ BN1 stats ----
// Thread t: edge-lane el=t>>4, channel quad c4=t&15 (float4). 16 edges per
// block-iteration, unroll 4 -> ~12 independent loads in flight per thread.
__global__ __launch_bounds__(256) void bn1_stats(const int* __restrict__ nbr,
                                                 const float4* __restrict__ yv4,
                                                 const float4* __restrict__ zv4,
                                                 const float* __restrict__ b1,
                                                 float* __restrict__ stats) {
  const int t  = threadIdx.x;
  const int c4 = t & 15;
  const int el = t >> 4;
  const float4 bo = reinterpret_cast<const float4*>(b1)[c4];
  float4 s1 = make_float4(0, 0, 0, 0), s2 = make_float4(0, 0, 0, 0);
#pragma unroll 4
  for (int e0 = blockIdx.x * 16; e0 < NEDGE; e0 += gridDim.x * 16) {
    int e  = e0 + el;
    int j  = nbr[e];
    int ic = e / KNN_K;
    float4 y = yv4[(size_t)j * 16 + c4];
    float4 z = zv4[(size_t)ic * 16 + c4];
    float sx = y.x + z.x + bo.x, sy = y.y + z.y + bo.y;
    float sz = y.z + z.z + bo.z, sw = y.w + z.w + bo.w;
    s1.x += sx; s1.y += sy; s1.z += sz; s1.w += sw;
    s2.x += sx * sx; s2.y += sy * sy; s2.z += sz * sz; s2.w += sw * sw;
  }
  // reduce the 4 edge-lanes within each wave (lanes l, l^16, l^32 share c4)
  s1.x += __shfl_xor(s1.x, 16); s1.y += __shfl_xor(s1.y, 16);
  s1.z += __shfl_xor(s1.z, 16); s1.w += __shfl_xor(s1.w, 16);
  s2.x += __shfl_xor(s2.x, 16); s2.y += __shfl_xor(s2.y, 16);
  s2.z += __shfl_xor(s2.z, 16); s2.w += __shfl_xor(s2.w, 16);
  s1.x += __shfl_xor(s1.x, 32); s1.y += __shfl_xor(s1.y, 32);
  s1.z += __shfl_xor(s1.z, 32); s1.w += __shfl_xor(s1.w, 32);
  s2.x += __shfl_xor(s2.x, 32); s2.y += __shfl_xor(s2.y, 32);
  s2.z += __shfl_xor(s2.z, 32); s2.w += __shfl_xor(s2.w, 32);
  __shared__ float ss[2][64];
  if (t < 128) { ss[0][t & 63] = 0.f; }
  __syncthreads();
  if ((t & 48) == 0) {  // lanes 0..15 of each wave
    atomicAdd(&ss[0][c4 * 4 + 0], s1.x); atomicAdd(&ss[0][c4 * 4 + 1], s1.y);
    atomicAdd(&ss[0][c4 * 4 + 2], s1.z); atomicAdd(&ss[0][c4 * 4 + 3], s1.w);
    atomicAdd(&ss[1][c4 * 4 + 0], s2.x); atomicAdd(&ss[1][c4 * 4 + 1], s2.y);
    atomicAdd(&ss[1][c4 * 4 + 2], s2.z); atomicAdd(&ss[1][c4 * 4 + 3], s2.w);
  }
  __syncthreads();
  if (t < 64)       atomicAdd(&stats[t], ss[0][t]);
  else if (t < 128) atomicAdd(&stats[64 + (t - 64)], ss[1][t - 64]);
}

// --------------------------------- fused BN1-apply + GEMM2 (+stats/scatter)
template <int MODE, bool STORE>
__global__ __launch_bounds__(256) void gemm2_pass(
    const int* __restrict__ nbr, const float* __restrict__ yv,
    const float* __restrict__ zv, const float* __restrict__ b1,
    const float* __restrict__ stats1, const float* __restrict__ g1,
    const float* __restrict__ beta1, const float* __restrict__ W2,
    const float* __restrict__ b2, float* __restrict__ h2s,
    float* __restrict__ stats2, const float* __restrict__ g2,
    const float* __restrict__ beta2, float* __restrict__ outp) {
  __shared__ float w2t[64][68];
  __shared__ float h1s[64][68];
  __shared__ float a1s[64], c1s[64], b1s[64];
  __shared__ float ss[2][64];
  const int t = threadIdx.x;
  constexpr float invE = 1.0f / NEDGE;
  for (int m = t; m < 4096; m += 256) {
    int o = m >> 6, c = m & 63;
    w2t[c][o] = W2[m];
  }
  if (t < 64) {
    float mu  = stats1[t] * invE;
    float var = stats1[64 + t] * invE - mu * mu;
    float a   = g1[t] * rsqrtf(var + 1e-5f);
    a1s[t] = a; c1s[t] = beta1[t] - mu * a; b1s[t] = b1[t];
  }
  const int eg = t >> 4, cg = t & 15;
  const int e0l = eg * 4, o0 = cg * 4;
  float b2r[4], a2r[4], c2r[4];
#pragma unroll
  for (int q = 0; q < 4; ++q) b2r[q] = b2[o0 + q];
  if (MODE == 1) {
#pragma unroll
    for (int q = 0; q < 4; ++q) {
      float mu  = stats2[o0 + q] * invE;
      float var = stats2[64 + o0 + q] * invE - mu * mu;
      float a   = g2[o0 + q] * rsqrtf(var + 1e-5f);
      a2r[q] = a; c2r[q] = beta2[o0 + q] - mu * a;
    }
  }
  float s1[4] = {0, 0, 0, 0}, s2[4] = {0, 0, 0, 0};
  const int ntiles = NEDGE / 64;
  for (int tile = blockIdx.x; tile < ntiles; tile += gridDim.x) {
    __syncthreads();
    const int ebase = tile * 64;
#pragma unroll
    for (int k = 0; k < 16; ++k) {
      int m = k * 256 + t;
      int el = m >> 6, o = m & 63;
      int e = ebase + el;
      int j  = nbr[e];
      int ic = e / KNN_K;
      float s = yv[(size_t)j * 64 + o] + zv[(size_t)ic * 64 + o] + b1s[o];
      float h = fmaf(s, a1s[o], c1s[o]);
      h1s[el][o] = h > 0.f ? h : 0.f;
    }
    __syncthreads();
    float acc[4][4];
#pragma unroll
    for (int r = 0; r < 4; ++r)
#pragma unroll
      for (int q = 0; q < 4; ++q) acc[r][q] = 0.f;
#pragma unroll 8
    for (int c = 0; c < 64; ++c) {
      float a0 = h1s[e0l + 0][c], a1 = h1s[e0l + 1][c];
      float a2 = h1s[e0l + 2][c], a3 = h1s[e0l + 3][c];
      float w0 = w2t[c][o0 + 0], w1 = w2t[c][o0 + 1];
      float w2v = w2t[c][o0 + 2], w3 = w2t[c][o0 + 3];
      acc[0][0] = fmaf(a0, w0, acc[0][0]); acc[0][1] = fmaf(a0, w1, acc[0][1]);
      acc[0][2] = fmaf(a0, w2v, acc[0][2]); acc[0][3] = fmaf(a0, w3, acc[0][3]);
      acc[1][0] = fmaf(a1, w0, acc[1][0]); acc[1][1] = fmaf(a1, w1, acc[1][1]);
      acc[1][2] = fmaf(a1, w2v, acc[1][2]); acc[1][3] = fmaf(a1, w3, acc[1][3]);
      acc[2][0] = fmaf(a2, w0, acc[2][0]); acc[2][1] = fmaf(a2, w1, acc[2][1]);
      acc[2][2] = fmaf(a2, w2v, acc[2][2]); acc[2][3] = fmaf(a2, w3, acc[2][3]);
      acc[3][0] = fmaf(a3, w0, acc[3][0]); acc[3][1] = fmaf(a3, w1, acc[3][1]);
      acc[3][2] = fmaf(a3, w2v, acc[3][2]); acc[3][3] = fmaf(a3, w3, acc[3][3]);
    }
    if constexpr (MODE == 0) {
#pragma unroll
      for (int r = 0; r < 4; ++r) {
        float v0 = acc[r][0] + b2r[0];
        float v1 = acc[r][1] + b2r[1];
        float v2 = acc[r][2] + b2r[2];
        float v3 = acc[r][3] + b2r[3];
        s1[0] += v0; s1[1] += v1; s1[2] += v2; s1[3] += v3;
        s2[0] += v0 * v0; s2[1] += v1 * v1; s2[2] += v2 * v2; s2[3] += v3 * v3;
        if constexpr (STORE) {
          float4 vv = make_float4(v0, v1, v2, v3);
          *reinterpret_cast<float4*>(&h2s[(size_t)(ebase + e0l + r) * 64 + o0]) = vv;
        }
      }
    } else {
#pragma unroll
      for (int r = 0; r < 4; ++r) {
        int row = nbr[ebase + e0l + r];
        int* op = reinterpret_cast<int*>(outp) + (size_t)row * 64 + o0;
#pragma unroll
        for (int q = 0; q < 4; ++q) {
          float v = fmaf(acc[r][q] + b2r[q], a2r[q], c2r[q]);
          v = v > 0.f ? v : 0.f;
          atomicMax(op + q, __float_as_int(v));
        }
      }
    }
  }
  if constexpr (MODE == 0) {
    __syncthreads();
    if (t < 64) { ss[0][t] = 0.f; ss[1][t] = 0.f; }
    __syncthreads();
#pragma unroll
    for (int q = 0; q < 4; ++q) {
      s1[q] += __shfl_xor(s1[q], 16);
      s1[q] += __shfl_xor(s1[q], 32);
      s2[q] += __shfl_xor(s2[q], 16);
      s2[q] += __shfl_xor(s2[q], 32);
    }
    if ((t & 48) == 0) {
#pragma unroll
      for (int q = 0; q < 4; ++q) {
        atomicAdd(&ss[0][o0 + q], s1[q]);
        atomicAdd(&ss[1][o0 + q], s2[q]);
      }
    }
    __syncthreads();
    if (t < 64)       atomicAdd(&stats2[t], ss[0][t]);
    else if (t < 128) atomicAdd(&stats2[t - 64 + 64], ss[1][t - 64]);
  }
}

// ---------------------------- per-row gather: BN2 apply + relu + max + store
__global__ __launch_bounds__(256) void gather_out(
    const float* __restrict__ h2s, const float* __restrict__ stats2,
    const float* __restrict__ g2, const float* __restrict__ beta2,
    const int* __restrict__ cnt, const int* __restrict__ rev,
    const int* __restrict__ ovf_cnt, const int* __restrict__ ovf,
    const int* __restrict__ nbr, float* __restrict__ outp) {
  const int lane = threadIdx.x & 63;
  const int row  = blockIdx.x * 4 + (threadIdx.x >> 6);
  constexpr float invE = 1.0f / NEDGE;
  float mu  = stats2[lane] * invE;
  float var = stats2[64 + lane] * invE - mu * mu;
  float a2  = g2[lane] * rsqrtf(var + 1e-5f);
  float c2  = beta2[lane] - mu * a2;
  float m = 0.f;  // relu floor doubles as empty-segment value
  int n = cnt[row]; n = n > REVCAP ? REVCAP : n;
  const int* rv = &rev[(size_t)row * REVCAP];
  for (int u = 0; u < n; ++u) {
    int e = rv[u];
    float v = h2s[(size_t)e * 64 + lane];
    float r = fmaf(v, a2, c2);
    m = r > m ? r : m;
  }
  int ov = ovf_cnt[0]; ov = ov > OVCAP ? OVCAP : ov;
  for (int u = 0; u < ov; ++u) {
    int e = ovf[u];
    if (nbr[e] == row) {
      float v = h2s[(size_t)e * 64 + lane];
      float r = fmaf(v, a2, c2);
      m = r > m ? r : m;
    }
  }
  outp[(size_t)row * 64 + lane] = m;
}

// --------------------------------------------------------------- launch ----
extern "C" void kernel_launch(void* const* d_in, const int* in_sizes, int n_in,
                              void* d_out, int out_size, void* d_ws, size_t ws_size,
                              hipStream_t stream) {
  (void)in_sizes; (void)n_in;
  const float* x     = (const float*)d_in[0];
  const float* pos   = (const float*)d_in[1];
  const float* W1    = (const float*)d_in[3];
  const float* b1    = (const float*)d_in[4];
  const float* g1    = (const float*)d_in[5];
  const float* beta1 = (const float*)d_in[6];
  const float* W2    = (const float*)d_in[7];
  const float* b2    = (const float*)d_in[8];
  const float* g2    = (const float*)d_in[9];
  const float* beta2 = (const float*)d_in[10];
  float* outp = (float*)d_out;

  char* w = (char*)d_ws;
  int*   nbr     = (int*)w;                            // 1,310,720 B
  float* yv      = (float*)(w + 1310720);              // 4,194,304 B
  float* zv      = (float*)(w + 5505024);              // 4,194,304 B
  float* stats   = (float*)(w + 9699328);              // 1,024 B ([0..127] bn1, [128..255] bn2)
  int*   cnt     = (int*)(w + 9700352);                // 65,536 B
  int*   ovf_cnt = (int*)(w + 9765888);                // 64 B
  int*   ovf     = (int*)(w + 9765952);                // 32,768 B
  int*   rev     = (int*)(w + 9798720);                // 8,388,608 B
  float* h2s     = (float*)(w + 18187328);             // 83,886,080 B (optional)
  const size_t NEED_BIG = 18187328ull + (size_t)NEDGE * 64 * 4;
  const bool big = ws_size >= NEED_BIG;

  hipMemsetAsync(stats, 0, 1024, stream);
  hipMemsetAsync(cnt, 0, 65536 + 64, stream);

  knn_kernel<<<NPT / 32, 256, 0, stream>>>(pos, nbr, cnt, ovf_cnt, ovf, rev);
  node_gemm<<<NPT / 4, 256, 0, stream>>>(x, W1, yv, zv);
  bn1_stats<<<512, 256, 0, stream>>>(nbr, (const float4*)yv, (const float4*)zv, b1, stats);
  if (big) {
    gemm2_pass<0, true><<<1024, 256, 0, stream>>>(
        nbr, yv, zv, b1, stats, g1, beta1, W2, b2, h2s, stats + 128, g2, beta2, nullptr);
    gather_out<<<NPT / 4, 256, 0, stream>>>(
        h2s, stats + 128, g2, beta2, cnt, rev, ovf_cnt, ovf, nbr, outp);
  } else {
    hipMemsetAsync(d_out, 0, (size_t)out_size * sizeof(float), stream);
    gemm2_pass<0, false><<<1024, 256, 0, stream>>>(
        nbr, yv, zv, b1, stats, g1, beta1, W2, b2, nullptr, stats + 128, g2, beta2, nullptr);
    gemm2_pass<1, false><<<1024, 256, 0, stream>>>(
        nbr, yv, zv, b1, stats, g1, beta1, W2, b2, nullptr, stats + 128, g2, beta2, outp);
  }
}

// Round 5
// 314.794 us; speedup vs baseline: 10.6957x; 1.1946x over previous
//
#include <hip/hip_runtime.h>

constexpr int BATCH = 8;
constexpr int PPC   = 2048;            // points per cloud
constexpr int NPT   = BATCH * PPC;     // 16384 points
constexpr int OCH   = 64;              // out channels (= in channels)
constexpr int KNN_K = 20;
constexpr int NEDGE = NPT * KNN_K;     // 327680 edges
constexpr int REVCAP = 128;            // per-row reverse-adjacency capacity
constexpr int OVCAP  = 8192;           // overflow list capacity

// ---------------------------------------------------------------- kNN ------
// Block = 16 points x 16 splits (256 threads). Each lane scans 128 candidates
// keeping a register top-20 of keys (d2_bits<<20 | index) reinterpreted as
// NON-NEGATIVE f64 (denormals) so v_min_f64/v_max_f64 give exact (d2,index)
// lexicographic order: sorted insert = kd[q] = max(kd[q-1], min(kd[q], ck)),
// 2 ops/slot, no vcc chains. Then a width-16 shfl min-tournament merges.
__global__ __launch_bounds__(256) void knn_kernel(const float* __restrict__ pos,
                                                  int* __restrict__ nbr,
                                                  int* __restrict__ cnt,
                                                  int* __restrict__ ovf_cnt,
                                                  int* __restrict__ ovf,
                                                  int* __restrict__ rev) {
  __shared__ float4 cps[8 * 257];  // region r at r*257 (+pad)
  const int t  = threadIdx.x;
  const int pl = t >> 4;                        // point-local 0..15
  const int s  = t & 15;                        // split 0..15
  const int i  = blockIdx.x * 16 + pl;          // this thread's point
  const int cbase = i & ~(PPC - 1);             // cloud base (uniform in block)

  for (int u = t; u < PPC; u += 256) {
    int j = cbase + u;
    float ax = pos[3 * j], ay = pos[3 * j + 1], az = pos[3 * j + 2];
    cps[(u >> 8) * 257 + (u & 255)] = make_float4(ax, ay, az, ax * ax + ay * ay + az * az);
  }
  __syncthreads();

  const int il = i - cbase;
  const float4 me = cps[(il >> 8) * 257 + (il & 255)];
  const float px = me.x, py = me.y, pz = me.z, sqi = me.w;

  const double SENT = __longlong_as_double(0x7FE0000000000000LL);  // huge, not inf/nan
  double kd[KNN_K];
#pragma unroll
  for (int q = 0; q < KNN_K; ++q) kd[q] = SENT;

  const int jbase = s * 128;
  const float4* __restrict__ cp = &cps[(s >> 1) * 257 + (s & 1) * 128];
  for (int u = 0; u < 128; ++u) {
    float4 c = cp[u];
    float d2 = sqi + c.w - 2.0f * (px * c.x + py * c.y + pz * c.z);
    d2 = d2 > 0.f ? d2 : 0.f;                  // keep sign bit 0
    int jl = jbase + u;
    unsigned long long ckb =
        ((unsigned long long)__float_as_uint(d2) << 20) | (unsigned)jl;
    double ck = __longlong_as_double((long long)ckb);
    ck = (jl == il) ? SENT : ck;
    // branch-free sorted insert: kd[q] = max(kd[q-1], min(kd[q], ck))
#pragma unroll
    for (int q = KNN_K - 1; q > 0; --q)
      kd[q] = fmax(kd[q - 1], fmin(kd[q], ck));
    kd[0] = fmin(kd[0], ck);
  }

  // 16-way merge: 20 rounds of width-16 min-tournament on the list heads.
  int res[KNN_K];
#pragma unroll
  for (int r = 0; r < KNN_K; ++r) {
    double w = kd[0];
#pragma unroll
    for (int m = 1; m < 16; m <<= 1) {
      double o = __shfl_xor(w, m, 16);
      w = fmin(w, o);
    }
    res[r] = (int)(__double_as_longlong(w) & 0xFFFFF);  // low 20 bits = index
    bool mine = (kd[0] == w);              // keys unique -> exactly one lane
#pragma unroll
    for (int q = 0; q < KNN_K - 1; ++q) kd[q] = mine ? kd[q + 1] : kd[q];
    kd[KNN_K - 1] = mine ? SENT : kd[KNN_K - 1];
  }
  if (s == 0) {
    int4* op = reinterpret_cast<int4*>(&nbr[(size_t)i * KNN_K]);
#pragma unroll
    for (int q = 0; q < 5; ++q)
      op[q] = make_int4(cbase + res[4 * q], cbase + res[4 * q + 1],
                        cbase + res[4 * q + 2], cbase + res[4 * q + 3]);
  }
  // reverse-CSR fill from registers: lane s handles q = s (and s+16 if s<4)
#pragma unroll
  for (int q0 = 0; q0 < 2; ++q0) {
    int q = s + q0 * 16;
    if (q < KNN_K) {
      int j = cbase + res[q];
      int e = i * KNN_K + q;
      int slot = atomicAdd(&cnt[j], 1);
      if (slot < REVCAP) rev[j * REVCAP + slot] = e;
      else { int ov = atomicAdd(ovf_cnt, 1); if (ov < OVCAP) ovf[ov] = e; }
    }
  }
}

// ------------------------------------------------- node-level layer-1 GEMM -
__global__ __launch_bounds__(256) void node_gemm(const float* __restrict__ x,
                                                 const float* __restrict__ W1,
                                                 float* __restrict__ yv,
                                                 float* __restrict__ zv) {
  __shared__ float wa[64][65];
  __shared__ float wb[64][65];
  __shared__ float xs[4][64];
  const int t = threadIdx.x;
  for (int m = t; m < 8192; m += 256) {
    int o = m >> 7, c2 = m & 127;
    float w = W1[m];
    if (c2 < 64) wa[c2][o] = w; else wb[c2 - 64][o] = w;
  }
  const int nl = t >> 6, o = t & 63;
  xs[nl][o] = x[(size_t)(blockIdx.x * 4 + nl) * 64 + o];
  __syncthreads();
  float accA = 0.f, accB = 0.f;
#pragma unroll 8
  for (int c = 0; c < 64; ++c) {
    float xv = xs[nl][c];
    accA = fmaf(xv, wa[c][o], accA);
    accB = fmaf(xv, wb[c][o], accB);
  }
  size_t n = (size_t)blockIdx.x * 4 + nl;
  yv[n * 64 + o] = accA - accB;
  zv[n * 64 + o] = accB;
}

// ------------------------------------------------------------ BN1 stats ----
__global__ __launch_bounds__(256) void bn1_stats(const int* __restrict__ nbr,
                                                 const float4* __restrict__ yv4,
                                                 const float4* __restrict__ zv4,
                                                 const float* __restrict__ b1,
                                                 float* __restrict__ stats) {
  const int t  = threadIdx.x;
  const int c4 = t & 15;
  const int el = t >> 4;
  const float4 bo = reinterpret_cast<const float4*>(b1)[c4];
  float4 s1 = make_float4(0, 0, 0, 0), s2 = make_float4(0, 0, 0, 0);
#pragma unroll 4
  for (int e0 = blockIdx.x * 16; e0 < NEDGE; e0 += gridDim.x * 16) {
    int e  = e0 + el;
    int j  = nbr[e];
    int ic = e / KNN_K;
    float4 y = yv4[(size_t)j * 16 + c4];
    float4 z = zv4[(size_t)ic * 16 + c4];
    float sx = y.x + z.x + bo.x, sy = y.y + z.y + bo.y;
    float sz = y.z + z.z + bo.z, sw = y.w + z.w + bo.w;
    s1.x += sx; s1.y += sy; s1.z += sz; s1.w += sw;
    s2.x += sx * sx; s2.y += sy * sy; s2.z += sz * sz; s2.w += sw * sw;
  }
  s1.x += __shfl_xor(s1.x, 16); s1.y += __shfl_xor(s1.y, 16);
  s1.z += __shfl_xor(s1.z, 16); s1.w += __shfl_xor(s1.w, 16);
  s2.x += __shfl_xor(s2.x, 16); s2.y += __shfl_xor(s2.y, 16);
  s2.z += __shfl_xor(s2.z, 16); s2.w += __shfl_xor(s2.w, 16);
  s1.x += __shfl_xor(s1.x, 32); s1.y += __shfl_xor(s1.y, 32);
  s1.z += __shfl_xor(s1.z, 32); s1.w += __shfl_xor(s1.w, 32);
  s2.x += __shfl_xor(s2.x, 32); s2.y += __shfl_xor(s2.y, 32);
  s2.z += __shfl_xor(s2.z, 32); s2.w += __shfl_xor(s2.w, 32);
  __shared__ float ss[2][64];
  if (t < 128) { ss[0][t & 63] = 0.f; }
  __syncthreads();
  if ((t & 48) == 0) {
    atomicAdd(&ss[0][c4 * 4 + 0], s1.x); atomicAdd(&ss[0][c4 * 4 + 1], s1.y);
    atomicAdd(&ss[0][c4 * 4 + 2], s1.z); atomicAdd(&ss[0][c4 * 4 + 3], s1.w);
    atomicAdd(&ss[1][c4 * 4 + 0], s2.x); atomicAdd(&ss[1][c4 * 4 + 1], s2.y);
    atomicAdd(&ss[1][c4 * 4 + 2], s2.z); atomicAdd(&ss[1][c4 * 4 + 3], s2.w);
  }
  __syncthreads();
  if (t < 64)       atomicAdd(&stats[t], ss[0][t]);
  else if (t < 128) atomicAdd(&stats[64 + (t - 64)], ss[1][t - 64]);
}

// --------------------------------- fused BN1-apply + GEMM2 (+stats/scatter)
template <int MODE, bool STORE>
__global__ __launch_bounds__(256) void gemm2_pass(
    const int* __restrict__ nbr, const float* __restrict__ yv,
    const float* __restrict__ zv, const float* __restrict__ b1,
    const float* __restrict__ stats1, const float* __restrict__ g1,
    const float* __restrict__ beta1, const float* __restrict__ W2,
    const float* __restrict__ b2, float* __restrict__ h2s,
    float* __restrict__ stats2, const float* __restrict__ g2,
    const float* __restrict__ beta2, float* __restrict__ outp) {
  __shared__ float w2t[64][68];
  __shared__ float h1s[64][68];
  __shared__ float a1s[64], c1s[64], b1s[64];
  __shared__ float ss[2][64];
  const int t = threadIdx.x;
  constexpr float invE = 1.0f / NEDGE;
  const float4* __restrict__ yv4 = (const float4*)yv;
  const float4* __restrict__ zv4 = (const float4*)zv;
  for (int m = t; m < 4096; m += 256) {
    int o = m >> 6, c = m & 63;
    w2t[c][o] = W2[m];
  }
  if (t < 64) {
    float mu  = stats1[t] * invE;
    float var = stats1[64 + t] * invE - mu * mu;
    float a   = g1[t] * rsqrtf(var + 1e-5f);
    a1s[t] = a; c1s[t] = beta1[t] - mu * a; b1s[t] = b1[t];
  }
  __syncthreads();
  const int eg = t >> 4, cg = t & 15;
  const int e0l = eg * 4, o0 = cg * 4;
  float b2r[4], a2r[4], c2r[4], a1r[4], c1r[4], b1r[4];
#pragma unroll
  for (int q = 0; q < 4; ++q) {
    b2r[q] = b2[o0 + q];
    a1r[q] = a1s[o0 + q]; c1r[q] = c1s[o0 + q]; b1r[q] = b1s[o0 + q];
  }
  if (MODE == 1) {
#pragma unroll
    for (int q = 0; q < 4; ++q) {
      float mu  = stats2[o0 + q] * invE;
      float var = stats2[64 + o0 + q] * invE - mu * mu;
      float a   = g2[o0 + q] * rsqrtf(var + 1e-5f);
      a2r[q] = a; c2r[q] = beta2[o0 + q] - mu * a;
    }
  }
  float s1[4] = {0, 0, 0, 0}, s2[4] = {0, 0, 0, 0};
  const int ntiles = NEDGE / 64;
  for (int tile = blockIdx.x; tile < ntiles; tile += gridDim.x) {
    __syncthreads();
    const int ebase = tile * 64;
    // stage 64 edges x 64 ch of BN1(relu(h1_pre)) into LDS, float4-wide
#pragma unroll
    for (int k = 0; k < 4; ++k) {
      int el = k * 16 + eg;
      int e  = ebase + el;
      int j  = nbr[e];
      int ic = e / KNN_K;
      float4 y = yv4[(size_t)j * 16 + cg];
      float4 z = zv4[(size_t)ic * 16 + cg];
      float4 h;
      h.x = fmaf(y.x + z.x + b1r[0], a1r[0], c1r[0]);
      h.y = fmaf(y.y + z.y + b1r[1], a1r[1], c1r[1]);
      h.z = fmaf(y.z + z.z + b1r[2], a1r[2], c1r[2]);
      h.w = fmaf(y.w + z.w + b1r[3], a1r[3], c1r[3]);
      h.x = h.x > 0.f ? h.x : 0.f; h.y = h.y > 0.f ? h.y : 0.f;
      h.z = h.z > 0.f ? h.z : 0.f; h.w = h.w > 0.f ? h.w : 0.f;
      *reinterpret_cast<float4*>(&h1s[el][o0]) = h;
    }
    __syncthreads();
    float acc[4][4];
#pragma unroll
    for (int r = 0; r < 4; ++r)
#pragma unroll
      for (int q = 0; q < 4; ++q) acc[r][q] = 0.f;
#pragma unroll 4
    for (int c4 = 0; c4 < 16; ++c4) {
      float4 h0 = *reinterpret_cast<const float4*>(&h1s[e0l + 0][c4 * 4]);
      float4 h1 = *reinterpret_cast<const float4*>(&h1s[e0l + 1][c4 * 4]);
      float4 h2 = *reinterpret_cast<const float4*>(&h1s[e0l + 2][c4 * 4]);
      float4 h3 = *reinterpret_cast<const float4*>(&h1s[e0l + 3][c4 * 4]);
      float4 w0 = *reinterpret_cast<const float4*>(&w2t[c4 * 4 + 0][o0]);
      float4 w1 = *reinterpret_cast<const float4*>(&w2t[c4 * 4 + 1][o0]);
      float4 w2 = *reinterpret_cast<const float4*>(&w2t[c4 * 4 + 2][o0]);
      float4 w3 = *reinterpret_cast<const float4*>(&w2t[c4 * 4 + 3][o0]);
#define GFMA(R, H)                                                       \
      acc[R][0] = fmaf(H.x, w0.x, acc[R][0]); acc[R][0] = fmaf(H.y, w1.x, acc[R][0]); \
      acc[R][0] = fmaf(H.z, w2.x, acc[R][0]); acc[R][0] = fmaf(H.w, w3.x, acc[R][0]); \
      acc[R][1] = fmaf(H.x, w0.y, acc[R][1]); acc[R][1] = fmaf(H.y, w1.y, acc[R][1]); \
      acc[R][1] = fmaf(H.z, w2.y, acc[R][1]); acc[R][1] = fmaf(H.w, w3.y, acc[R][1]); \
      acc[R][2] = fmaf(H.x, w0.z, acc[R][2]); acc[R][2] = fmaf(H.y, w1.z, acc[R][2]); \
      acc[R][2] = fmaf(H.z, w2.z, acc[R][2]); acc[R][2] = fmaf(H.w, w3.z, acc[R][2]); \
      acc[R][3] = fmaf(H.x, w0.w, acc[R][3]); acc[R][3] = fmaf(H.y, w1.w, acc[R][3]); \
      acc[R][3] = fmaf(H.z, w2.w, acc[R][3]); acc[R][3] = fmaf(H.w, w3.w, acc[R][3]);
      GFMA(0, h0) GFMA(1, h1) GFMA(2, h2) GFMA(3, h3)
#undef GFMA
    }
    if constexpr (MODE == 0) {
#pragma unroll
      for (int r = 0; r < 4; ++r) {
        float v0 = acc[r][0] + b2r[0];
        float v1 = acc[r][1] + b2r[1];
        float v2 = acc[r][2] + b2r[2];
        float v3 = acc[r][3] + b2r[3];
        s1[0] += v0; s1[1] += v1; s1[2] += v2; s1[3] += v3;
        s2[0] += v0 * v0; s2[1] += v1 * v1; s2[2] += v2 * v2; s2[3] += v3 * v3;
        if constexpr (STORE) {
          float4 vv = make_float4(v0, v1, v2, v3);
          *reinterpret_cast<float4*>(&h2s[(size_t)(ebase + e0l + r) * 64 + o0]) = vv;
        }
      }
    } else {
#pragma unroll
      for (int r = 0; r < 4; ++r) {
        int row = nbr[ebase + e0l + r];
        int* op = reinterpret_cast<int*>(outp) + (size_t)row * 64 + o0;
#pragma unroll
        for (int q = 0; q < 4; ++q) {
          float v = fmaf(acc[r][q] + b2r[q], a2r[q], c2r[q]);
          v = v > 0.f ? v : 0.f;
          atomicMax(op + q, __float_as_int(v));
        }
      }
    }
  }
  if constexpr (MODE == 0) {
    __syncthreads();
    if (t < 64) { ss[0][t] = 0.f; ss[1][t] = 0.f; }
    __syncthreads();
#pragma unroll
    for (int q = 0; q < 4; ++q) {
      s1[q] += __shfl_xor(s1[q], 16);
      s1[q] += __shfl_xor(s1[q], 32);
      s2[q] += __shfl_xor(s2[q], 16);
      s2[q] += __shfl_xor(s2[q], 32);
    }
    if ((t & 48) == 0) {
#pragma unroll
      for (int q = 0; q < 4; ++q) {
        atomicAdd(&ss[0][o0 + q], s1[q]);
        atomicAdd(&ss[1][o0 + q], s2[q]);
      }
    }
    __syncthreads();
    if (t < 64)       atomicAdd(&stats2[t], ss[0][t]);
    else if (t < 128) atomicAdd(&stats2[t - 64 + 64], ss[1][t - 64]);
  }
}

// ---------------------------- per-row gather: BN2 apply + relu + max + store
__global__ __launch_bounds__(256) void gather_out(
    const float* __restrict__ h2s, const float* __restrict__ stats2,
    const float* __restrict__ g2, const float* __restrict__ beta2,
    const int* __restrict__ cnt, const int* __restrict__ rev,
    const int* __restrict__ ovf_cnt, const int* __restrict__ ovf,
    const int* __restrict__ nbr, float* __restrict__ outp) {
  const int lane = threadIdx.x & 63;
  const int row  = blockIdx.x * 4 + (threadIdx.x >> 6);
  constexpr float invE = 1.0f / NEDGE;
  float mu  = stats2[lane] * invE;
  float var = stats2[64 + lane] * invE - mu * mu;
  float a2  = g2[lane] * rsqrtf(var + 1e-5f);
  float c2  = beta2[lane] - mu * a2;
  float m = 0.f;  // relu floor doubles as empty-segment value
  int n = cnt[row]; n = n > REVCAP ? REVCAP : n;
  const int* rv = &rev[(size_t)row * REVCAP];
  for (int u = 0; u < n; ++u) {
    int e = rv[u];
    float v = h2s[(size_t)e * 64 + lane];
    float r = fmaf(v, a2, c2);
    m = r > m ? r : m;
  }
  int ov = ovf_cnt[0]; ov = ov > OVCAP ? OVCAP : ov;
  for (int u = 0; u < ov; ++u) {
    int e = ovf[u];
    if (nbr[e] == row) {
      float v = h2s[(size_t)e * 64 + lane];
      float r = fmaf(v, a2, c2);
      m = r > m ? r : m;
    }
  }
  outp[(size_t)row * 64 + lane] = m;
}

// --------------------------------------------------------------- launch ----
extern "C" void kernel_launch(void* const* d_in, const int* in_sizes, int n_in,
                              void* d_out, int out_size, void* d_ws, size_t ws_size,
                              hipStream_t stream) {
  (void)in_sizes; (void)n_in;
  const float* x     = (const float*)d_in[0];
  const float* pos   = (const float*)d_in[1];
  const float* W1    = (const float*)d_in[3];
  const float* b1    = (const float*)d_in[4];
  const float* g1    = (const float*)d_in[5];
  const float* beta1 = (const float*)d_in[6];
  const float* W2    = (const float*)d_in[7];
  const float* b2    = (const float*)d_in[8];
  const float* g2    = (const float*)d_in[9];
  const float* beta2 = (const float*)d_in[10];
  float* outp = (float*)d_out;

  char* w = (char*)d_ws;
  int*   nbr     = (int*)w;                            // 1,310,720 B
  float* yv      = (float*)(w + 1310720);              // 4,194,304 B
  float* zv      = (float*)(w + 5505024);              // 4,194,304 B
  float* stats   = (float*)(w + 9699328);              // 1,024 B
  int*   cnt     = (int*)(w + 9700352);                // 65,536 B
  int*   ovf_cnt = (int*)(w + 9765888);                // 64 B
  int*   ovf     = (int*)(w + 9765952);                // 32,768 B
  int*   rev     = (int*)(w + 9798720);                // 8,388,608 B
  float* h2s     = (float*)(w + 18187328);             // 83,886,080 B (optional)
  const size_t NEED_BIG = 18187328ull + (size_t)NEDGE * 64 * 4;
  const bool big = ws_size >= NEED_BIG;

  hipMemsetAsync(stats, 0, 1024, stream);
  hipMemsetAsync(cnt, 0, 65536 + 64, stream);

  knn_kernel<<<NPT / 16, 256, 0, stream>>>(pos, nbr, cnt, ovf_cnt, ovf, rev);
  node_gemm<<<NPT / 4, 256, 0, stream>>>(x, W1, yv, zv);
  bn1_stats<<<512, 256, 0, stream>>>(nbr, (const float4*)yv, (const float4*)zv, b1, stats);
  if (big) {
    gemm2_pass<0, true><<<1024, 256, 0, stream>>>(
        nbr, yv, zv, b1, stats, g1, beta1, W2, b2, h2s, stats + 128, g2, beta2, nullptr);
    gather_out<<<NPT / 4, 256, 0, stream>>>(
        h2s, stats + 128, g2, beta2, cnt, rev, ovf_cnt, ovf, nbr, outp);
  } else {
    hipMemsetAsync(d_out, 0, (size_t)out_size * sizeof(float), stream);
    gemm2_pass<0, false><<<1024, 256, 0, stream>>>(
        nbr, yv, zv, b1, stats, g1, beta1, W2, b2, nullptr, stats + 128, g2, beta2, nullptr);
    gemm2_pass<1, false><<<1024, 256, 0, stream>>>(
        nbr, yv, zv, b1, stats, g1, beta1, W2, b2, nullptr, stats + 128, g2, beta2, outp);
  }
}